// Round 6
// baseline (1239.505 us; speedup 1.0000x reference)
//
#include <hip/hip_runtime.h>
#include <hip/hip_bf16.h>
#include <math.h>

using bf16 = __hip_bfloat16;
typedef __attribute__((ext_vector_type(8))) short s8v;
typedef __attribute__((ext_vector_type(4))) float f32x4;

#define D_MODEL 1024
#define NB 8
#define SEQ 1024
#define NHEAD 16
#define HD 64
#define MOE_H 2048
#define TOKENS (NB*SEQ)
#define QKV_STR 3072

#define GLDS(g, l) __builtin_amdgcn_global_load_lds( \
    (const __attribute__((address_space(1))) void*)(g), \
    (__attribute__((address_space(3))) void*)(l), 16, 0, 0)

// ---------------- fp32 -> bf16 convert ----------------
__global__ void f2b_k(const float* __restrict__ in, bf16* __restrict__ out, int n) {
    int i = blockIdx.x * blockDim.x + threadIdx.x;
    int stride = gridDim.x * blockDim.x;
    for (; i < n; i += stride) out[i] = __float2bfloat16(in[i]);
}

// ---------------- decomposition: trend + seasonal (LDS-tiled stencil) ----------------
#define TN 128
#define TD 64
__global__ __launch_bounds__(256) void decomp_k(
    const float* __restrict__ x, const float* __restrict__ alpha,
    const float* __restrict__ dw7, const float* __restrict__ dw25,
    const float* __restrict__ dw49, float* __restrict__ Tr, float* __restrict__ S)
{
    __shared__ float xs[TN + 48][TD];
    const int n0 = blockIdx.x * TN, d0 = blockIdx.y * TD, b = blockIdx.z;
    for (int i = threadIdx.x; i < (TN + 48) * (TD / 4); i += 256) {
        int r = i / (TD / 4), c4 = (i % (TD / 4)) * 4;
        int n = n0 + r - 24;
        if (n < 0) n = -n;
        if (n > SEQ - 1) n = 2 * (SEQ - 1) - n;
        *(float4*)&xs[r][c4] =
            *(const float4*)&x[((size_t)(b * SEQ + n)) * D_MODEL + d0 + c4];
    }
    float a0 = alpha[0], a1 = alpha[1], a2 = alpha[2];
    float mx = fmaxf(a0, fmaxf(a1, a2));
    float e0 = __expf(a0 - mx), e1 = __expf(a1 - mx), e2 = __expf(a2 - mx);
    float inv = 1.0f / (e0 + e1 + e2);
    float w7 = e0 * inv, w25 = e1 * inv, w49 = e2 * inv;
    const int dl = threadIdx.x & 63;
    const int nt = threadIdx.x >> 6;
    const int d = d0 + dl;
    float w[49];
    #pragma unroll
    for (int j = 0; j < 49; j++) {
        float v = w49 * dw49[d * 49 + j];
        if (j >= 12 && j < 37) v += w25 * dw25[d * 25 + j - 12];
        if (j >= 21 && j < 28) v += w7 * dw7[d * 7 + j - 21];
        w[j] = v;
    }
    __syncthreads();
    for (int nl = nt; nl < TN; nl += 4) {
        float acc = 0.f;
        #pragma unroll
        for (int j = 0; j < 49; j++) acc = fmaf(xs[nl + j][dl], w[j], acc);
        size_t idx = ((size_t)(b * SEQ + n0 + nl)) * D_MODEL + d;
        Tr[idx] = acc;
        S[idx] = xs[nl + 24][dl] - acc;
    }
}

// ---------------- LayerNorm (fp32 in, bf16 out, optional fp32 out) ----------------
__global__ __launch_bounds__(256) void ln_k(
    const float* __restrict__ x, const float* __restrict__ g, const float* __restrict__ b,
    bf16* __restrict__ ob, float* __restrict__ of)
{
    int row = blockIdx.x, t = threadIdx.x;
    const float* xr = x + (size_t)row * D_MODEL;
    float s = 0.f, s2 = 0.f;
    for (int d = t; d < D_MODEL; d += 256) { float v = xr[d]; s += v; s2 += v * v; }
    #pragma unroll
    for (int o = 32; o > 0; o >>= 1) { s += __shfl_down(s, o); s2 += __shfl_down(s2, o); }
    __shared__ float sh[8];
    int wid = t >> 6, lane = t & 63;
    if (lane == 0) { sh[wid] = s; sh[4 + wid] = s2; }
    __syncthreads();
    if (t == 0) {
        float ts = sh[0] + sh[1] + sh[2] + sh[3];
        float t2 = sh[4] + sh[5] + sh[6] + sh[7];
        float m = ts / D_MODEL;
        float var = t2 / D_MODEL - m * m;
        sh[0] = m; sh[1] = rsqrtf(var + 1e-5f);
    }
    __syncthreads();
    float m = sh[0], rs = sh[1];
    for (int d = t; d < D_MODEL; d += 256) {
        float v = (xr[d] - m) * rs * g[d] + b[d];
        ob[(size_t)row * D_MODEL + d] = __float2bfloat16(v);
        if (of) of[(size_t)row * D_MODEL + d] = v;
    }
}

// ---------------- bf16 MFMA GEMM, m97-style global_load_lds staging ----------------
// C[M,O] = A[M,K] @ B[O,K]^T (+bias)(+gelu)
// OMODE 0: fp32 out (+resid), 1: bf16 out, 2: fp32 accumulate += rowscale*v
// GMODE 0: dense; 1: gather A rows via row_map (store compact); 2: scatter store via row_map
template<int ACT, int OMODE, int GMODE>
__global__ __launch_bounds__(256) void gemm_nt(
    const bf16* __restrict__ A, const bf16* __restrict__ B,
    const float* __restrict__ bias, const float* resid,
    const float* __restrict__ rowscale, int rs_stride,
    void* C, int M, int K, int O,
    const int* __restrict__ row_map, const int* __restrict__ cnt_ptr)
{
    const int bm = blockIdx.x, bn = blockIdx.y;
    int M_act = M;
    if (GMODE != 0) {
        M_act = *cnt_ptr;
        if (bm * 128 >= M_act) return;
    }
    __shared__ bf16 As[128][64];   // unpadded: required by global_load_lds lane pattern
    __shared__ bf16 Bs[128][64];
    const int t = threadIdx.x;
    const int lane = t & 63, wid = t >> 6;
    const int wm = wid >> 1, wn = wid & 1;
    f32x4 acc[4][4] = {};
    const int lr = t >> 3;          // staging row within pass (0..31)
    const int lcb = (t & 7) * 8;    // staging col element (0,8,...,56)
    const bf16* arow[4]; const bf16* brow[4];
    #pragma unroll
    for (int p = 0; p < 4; p++) {
        int r = p * 32 + lr;
        int ar;
        if (GMODE == 1) { int gr = bm * 128 + r; ar = row_map[gr < M_act ? gr : M_act - 1]; }
        else ar = bm * 128 + r;
        arow[p] = A + (size_t)ar * K + lcb;
        brow[p] = B + (size_t)(bn * 128 + r) * K + lcb;
    }
    for (int k0 = 0; k0 < K; k0 += 64) {
        #pragma unroll
        for (int p = 0; p < 4; p++) {
            int r = p * 32 + lr;
            GLDS(arow[p] + k0, &As[r][lcb]);
            GLDS(brow[p] + k0, &Bs[r][lcb]);
        }
        __syncthreads();    // compiler emits vmcnt(0) drain before s_barrier
        const int fr = lane & 15, fq = (lane >> 4) * 8;
        #pragma unroll
        for (int kk = 0; kk < 64; kk += 32) {
            s8v af[4], bfr[4];
            #pragma unroll
            for (int i = 0; i < 4; i++) {
                af[i]  = *(const s8v*)&As[wm * 64 + i * 16 + fr][kk + fq];
                bfr[i] = *(const s8v*)&Bs[wn * 64 + i * 16 + fr][kk + fq];
            }
            #pragma unroll
            for (int i = 0; i < 4; i++)
                #pragma unroll
                for (int j = 0; j < 4; j++)
                    acc[i][j] = __builtin_amdgcn_mfma_f32_16x16x32_bf16(af[i], bfr[j], acc[i][j], 0, 0, 0);
        }
        __syncthreads();
    }
    const int cr = lane & 15, quad = lane >> 4;
    #pragma unroll
    for (int i = 0; i < 4; i++) {
        #pragma unroll
        for (int r = 0; r < 4; r++) {
            int row = bm * 128 + wm * 64 + i * 16 + quad * 4 + r;
            if (GMODE != 0 && row >= M_act) continue;
            int srow = (GMODE == 2) ? row_map[row] : row;
            #pragma unroll
            for (int j = 0; j < 4; j++) {
                int col = bn * 128 + wn * 64 + j * 16 + cr;
                float v = acc[i][j][r];
                if (bias) v += bias[col];
                if (ACT == 1) v = 0.5f * v * (1.0f + erff(v * 0.70710678118f));
                size_t idx = (size_t)srow * O + col;
                if (OMODE == 0) {
                    float rv = resid ? resid[idx] : 0.0f;
                    ((float*)C)[idx] = rv + v;
                } else if (OMODE == 1) {
                    ((bf16*)C)[idx] = __float2bfloat16(v);
                } else {
                    ((float*)C)[idx] += rowscale[(size_t)srow * rs_stride] * v;
                }
            }
        }
    }
}

// ---------------- MFMA flash attention with ALiBi, fixed-shift softmax ----------------
// QKV interleaved buffer, row stride 3072 (Q at +0, K at +1024, V at +2048)
__global__ __launch_bounds__(256) void attn_k(
    const bf16* __restrict__ QKV, bf16* __restrict__ Y)
{
    __shared__ bf16 Ks[64][72];
    __shared__ bf16 Vt[64][66];
    __shared__ bf16 Pw[4][32][72];
    const int t = threadIdx.x;
    const int wave = t >> 6, lane = t & 63;
    const int qm = lane & 15, quad = lane >> 4;
    const int b = blockIdx.z, h = blockIdx.y;
    const int qbase = blockIdx.x * 128 + wave * 32;
    const float slope = exp2f(-0.5f * (float)(h + 1));

    s8v qa[2][2];
    #pragma unroll
    for (int g = 0; g < 2; g++) {
        const bf16* qp = QKV + ((size_t)(b * SEQ + qbase + g * 16 + qm)) * QKV_STR + h * HD;
        qa[g][0] = *(const s8v*)&qp[quad * 8];
        qa[g][1] = *(const s8v*)&qp[32 + quad * 8];
    }

    f32x4 o[2][4] = {};
    float l[2][4] = {};

    const int sr = t >> 2;
    const int scc = (t & 3) * 16;

    for (int k0 = 0; k0 < SEQ; k0 += 64) {
        __syncthreads();
        const bf16* kp = QKV + ((size_t)(b * SEQ + k0 + sr)) * QKV_STR + 1024 + h * HD + scc;
        const bf16* vp = kp + 1024;
        s8v k0v = *(const s8v*)&kp[0];
        s8v k1v = *(const s8v*)&kp[8];
        s8v v0 = *(const s8v*)&vp[0];
        s8v v1 = *(const s8v*)&vp[8];
        *(s8v*)&Ks[sr][scc] = k0v;
        *(s8v*)&Ks[sr][scc + 8] = k1v;
        #pragma unroll
        for (int j = 0; j < 8; j++) {
            Vt[scc + j][sr]     = ((const bf16*)&v0)[j];
            Vt[scc + 8 + j][sr] = ((const bf16*)&v1)[j];
        }
        __syncthreads();
        #pragma unroll
        for (int g = 0; g < 2; g++) {
            f32x4 scr[4];
            #pragma unroll
            for (int jt = 0; jt < 4; jt++) {
                f32x4 z = {};
                s8v b0 = *(const s8v*)&Ks[jt * 16 + qm][quad * 8];
                s8v b1 = *(const s8v*)&Ks[jt * 16 + qm][32 + quad * 8];
                z = __builtin_amdgcn_mfma_f32_16x16x32_bf16(qa[g][0], b0, z, 0, 0, 0);
                z = __builtin_amdgcn_mfma_f32_16x16x32_bf16(qa[g][1], b1, z, 0, 0, 0);
                scr[jt] = z;
            }
            #pragma unroll
            for (int jt = 0; jt < 4; jt++) {
                int kcol = k0 + jt * 16 + qm;
                #pragma unroll
                for (int r = 0; r < 4; r++) {
                    int qrow = qbase + g * 16 + quad * 4 + r;
                    float dist = (float)max(kcol - qrow, 0);
                    float pf = __expf(fmaf(scr[jt][r], 0.125f, fmaf(-slope, dist, -8.0f)));
                    bf16 pb = __float2bfloat16(pf);
                    l[g][r] += __bfloat162float(pb);
                    Pw[wave][g * 16 + quad * 4 + r][jt * 16 + qm] = pb;
                }
            }
        }
        __builtin_amdgcn_wave_barrier();
        #pragma unroll
        for (int g = 0; g < 2; g++) {
            s8v pa0 = *(const s8v*)&Pw[wave][g * 16 + qm][quad * 8];
            s8v pa1 = *(const s8v*)&Pw[wave][g * 16 + qm][32 + quad * 8];
            #pragma unroll
            for (int dt = 0; dt < 4; dt++) {
                s8v vb0 = *(const s8v*)&Vt[dt * 16 + qm][quad * 8];
                s8v vb1 = *(const s8v*)&Vt[dt * 16 + qm][32 + quad * 8];
                o[g][dt] = __builtin_amdgcn_mfma_f32_16x16x32_bf16(pa0, vb0, o[g][dt], 0, 0, 0);
                o[g][dt] = __builtin_amdgcn_mfma_f32_16x16x32_bf16(pa1, vb1, o[g][dt], 0, 0, 0);
            }
        }
    }
    #pragma unroll
    for (int g = 0; g < 2; g++)
        #pragma unroll
        for (int r = 0; r < 4; r++) {
            float s = l[g][r];
            s += __shfl_xor(s, 1); s += __shfl_xor(s, 2);
            s += __shfl_xor(s, 4); s += __shfl_xor(s, 8);
            l[g][r] = 1.0f / s;
        }
    #pragma unroll
    for (int g = 0; g < 2; g++)
        #pragma unroll
        for (int dt = 0; dt < 4; dt++)
            #pragma unroll
            for (int r = 0; r < 4; r++) {
                size_t idx = ((size_t)(b * SEQ + qbase + g * 16 + quad * 4 + r)) * D_MODEL + h * HD + dt * 16 + qm;
                Y[idx] = __float2bfloat16(o[g][dt][r] * l[g][r]);
            }
}

// ---------------- router: gates, top-2 weights, aux, per-expert token lists ----------------
__global__ __launch_bounds__(256) void router_k(
    const float* __restrict__ xf, const float* __restrict__ rw,
    float* __restrict__ wts, float* __restrict__ auxb,
    int* __restrict__ cnt, int* __restrict__ elist)
{
    const int wave = threadIdx.x >> 6, lane = threadIdx.x & 63;
    float4 w[4][4];
    #pragma unroll
    for (int e = 0; e < 4; e++)
        #pragma unroll
        for (int c = 0; c < 4; c++)
            w[e][c] = *(const float4*)&rw[e * D_MODEL + lane * 16 + c * 4];
    float ag[4] = {0.f, 0.f, 0.f, 0.f};
    float ac[4] = {0.f, 0.f, 0.f, 0.f};
    __shared__ int sel[16][2];
    __shared__ float sh[4][8];
    const int t0 = (blockIdx.x * 4 + wave) * 4;
    #pragma unroll
    for (int i = 0; i < 4; i++) {
        const int tk = t0 + i;
        const float* xr = xf + (size_t)tk * D_MODEL + lane * 16;
        float4 xv[4];
        #pragma unroll
        for (int c = 0; c < 4; c++) xv[c] = *(const float4*)&xr[c * 4];
        float p[4] = {0.f, 0.f, 0.f, 0.f};
        #pragma unroll
        for (int e = 0; e < 4; e++)
            #pragma unroll
            for (int c = 0; c < 4; c++) {
                p[e] = fmaf(xv[c].x, w[e][c].x, p[e]);
                p[e] = fmaf(xv[c].y, w[e][c].y, p[e]);
                p[e] = fmaf(xv[c].z, w[e][c].z, p[e]);
                p[e] = fmaf(xv[c].w, w[e][c].w, p[e]);
            }
        #pragma unroll
        for (int o = 1; o < 64; o <<= 1) {
            p[0] += __shfl_xor(p[0], o); p[1] += __shfl_xor(p[1], o);
            p[2] += __shfl_xor(p[2], o); p[3] += __shfl_xor(p[3], o);
        }
        float g[4];
        float mx = fmaxf(fmaxf(p[0], p[1]), fmaxf(p[2], p[3]));
        float se = 0.f;
        #pragma unroll
        for (int e = 0; e < 4; e++) { g[e] = __expf(p[e] - mx); se += g[e]; }
        #pragma unroll
        for (int e = 0; e < 4; e++) g[e] /= se;
        int i1 = 0; float v1 = g[0];
        #pragma unroll
        for (int e = 1; e < 4; e++) if (g[e] > v1) { v1 = g[e]; i1 = e; }
        int i2 = -1; float v2 = -1.f;
        #pragma unroll
        for (int e = 0; e < 4; e++) if (e != i1 && g[e] > v2) { v2 = g[e]; i2 = e; }
        float sw = fmaxf(v1 + v2, 1e-9f);
        if (lane < 4) {
            float wv = (lane == i1) ? v1 / sw : ((lane == i2) ? v2 / sw : 0.f);
            wts[(size_t)tk * 4 + lane] = wv;
        }
        if (lane == 0) {
            #pragma unroll
            for (int e = 0; e < 4; e++) ag[e] += g[e];
            ac[i1] += 1.f; ac[i2] += 1.f;
            sel[wave * 4 + i][0] = i1;
            sel[wave * 4 + i][1] = i2;
        }
    }
    if (lane == 0)
        #pragma unroll
        for (int e = 0; e < 4; e++) { sh[wave][e] = ag[e]; sh[wave][4 + e] = ac[e]; }
    __syncthreads();
    if (threadIdx.x < 8) {
        float s = sh[0][threadIdx.x] + sh[1][threadIdx.x] + sh[2][threadIdx.x] + sh[3][threadIdx.x];
        atomicAdd(&auxb[threadIdx.x], s);
    }
    if (threadIdx.x < 4) {
        const int e = threadIdx.x;
        int loc[16]; int c = 0;
        #pragma unroll
        for (int s = 0; s < 16; s++)
            if (sel[s][0] == e || sel[s][1] == e) loc[c++] = blockIdx.x * 16 + s;
        if (c) {
            int base = atomicAdd(&cnt[e], c);
            for (int k = 0; k < c; k++) elist[e * TOKENS + base + k] = loc[k];
        }
    }
}

// ---------------- final: out = x_s + depthwise-conv5(Tr) + tb ----------------
__global__ __launch_bounds__(256) void final_k(
    const float* __restrict__ xs, const float* __restrict__ Tr,
    const float* __restrict__ tw, const float* __restrict__ tb, float* __restrict__ out)
{
    int n = blockIdx.x, b = blockIdx.y, t = threadIdx.x;
    for (int d = t; d < D_MODEL; d += 256) {
        float acc = tb[d];
        #pragma unroll
        for (int j = 0; j < 5; j++) {
            int i = n + j - 2;
            if (i >= 0 && i < SEQ)
                acc += Tr[((size_t)(b * SEQ + i)) * D_MODEL + d] * tw[d * 5 + j];
        }
        size_t idx = ((size_t)(b * SEQ + n)) * D_MODEL + d;
        out[idx] = xs[idx] + acc;
    }
}

__global__ void aux_k(const float* __restrict__ ab, float* __restrict__ out) {
    if (threadIdx.x == 0 && blockIdx.x == 0) {
        float a = 0.f;
        for (int e = 0; e < 4; e++)
            a += (ab[e] / (float)TOKENS) * (ab[4 + e] / (float)TOKENS);
        out[0] = 4.0f * a;
    }
}

extern "C" void kernel_launch(void* const* d_in, const int* in_sizes, int n_in,
                              void* d_out, int out_size, void* d_ws, size_t ws_size,
                              hipStream_t stream)
{
    const float* x    = (const float*)d_in[0];
    const float* qw   = (const float*)d_in[1];
    const float* qb   = (const float*)d_in[2];
    const float* kw   = (const float*)d_in[3];
    const float* kb   = (const float*)d_in[4];
    const float* vw   = (const float*)d_in[5];
    const float* vb   = (const float*)d_in[6];
    const float* ow   = (const float*)d_in[7];
    const float* ob   = (const float*)d_in[8];
    const float* n1g  = (const float*)d_in[9];
    const float* n1b  = (const float*)d_in[10];
    const float* n2g  = (const float*)d_in[11];
    const float* n2b  = (const float*)d_in[12];
    const float* alpha= (const float*)d_in[13];
    const float* dw7  = (const float*)d_in[14];
    const float* dw25 = (const float*)d_in[15];
    const float* dw49 = (const float*)d_in[16];
    const float* rw   = (const float*)d_in[17];
    const float* ew1  = (const float*)d_in[18];
    const float* eb1  = (const float*)d_in[19];
    const float* ew2  = (const float*)d_in[20];
    const float* eb2  = (const float*)d_in[21];
    const float* tw   = (const float*)d_in[22];
    const float* tb   = (const float*)d_in[23];

    char* ws = (char*)d_ws;
    const size_t MBy = 1ull << 20;
    float* S    = (float*)(ws + 0 * MBy);     // 32MB: seasonal -> x_s
    float* Tr   = (float*)(ws + 32 * MBy);    // 32MB
    float* XF   = (float*)(ws + 64 * MBy);    // 32MB
    bf16*  SNB  = (bf16*)(ws + 96 * MBy);     // 16MB: LN1 out; reused for Y
    bf16*  QKVB = (bf16*)(ws + 112 * MBy);    // 48MB: fused QKV out; reused for H
    bf16*  XFB  = (bf16*)(ws + 160 * MBy);    // 16MB
    bf16*  WQKV = (bf16*)(ws + 176 * MBy);    // 6MB: [3072][1024]
    bf16*  WO   = (bf16*)(ws + 182 * MBy);    // 2MB
    bf16*  WE1  = (bf16*)(ws + 184 * MBy);    // 16MB
    bf16*  WE2  = (bf16*)(ws + 200 * MBy);    // 16MB
    float* WTS  = (float*)(ws + 216 * MBy);
    float* AUXB = (float*)(ws + 217 * MBy);   // 8 floats
    int*   CNT  = (int*)(AUXB + 8);           // 4 ints
    int*   ELST = (int*)(ws + 218 * MBy);     // 4*8192 ints
    float* BQKV = (float*)(ws + 219 * MBy);   // 3072 floats
    bf16*  YB = SNB;
    bf16*  HB = QKVB;

    // weight conversions; QKV weights concatenated [WQ;WK;WV]
    f2b_k<<<2048, 256, 0, stream>>>(qw, WQKV, D_MODEL * D_MODEL);
    f2b_k<<<2048, 256, 0, stream>>>(kw, WQKV + D_MODEL * D_MODEL, D_MODEL * D_MODEL);
    f2b_k<<<2048, 256, 0, stream>>>(vw, WQKV + 2 * D_MODEL * D_MODEL, D_MODEL * D_MODEL);
    f2b_k<<<2048, 256, 0, stream>>>(ow, WO, D_MODEL * D_MODEL);
    f2b_k<<<4096, 256, 0, stream>>>(ew1, WE1, 4 * MOE_H * D_MODEL);
    f2b_k<<<4096, 256, 0, stream>>>(ew2, WE2, 4 * D_MODEL * MOE_H);
    hipMemcpyAsync(BQKV,        qb, D_MODEL * 4, hipMemcpyDeviceToDevice, stream);
    hipMemcpyAsync(BQKV + 1024, kb, D_MODEL * 4, hipMemcpyDeviceToDevice, stream);
    hipMemcpyAsync(BQKV + 2048, vb, D_MODEL * 4, hipMemcpyDeviceToDevice, stream);

    decomp_k<<<dim3(SEQ / TN, D_MODEL / TD, NB), 256, 0, stream>>>(x, alpha, dw7, dw25, dw49, Tr, S);

    ln_k<<<TOKENS, 256, 0, stream>>>(S, n1g, n1b, SNB, nullptr);

    // fused QKV projection
    gemm_nt<0, 1, 0><<<dim3(64, 24), 256, 0, stream>>>(SNB, WQKV, BQKV, nullptr, nullptr, 0, QKVB, TOKENS, D_MODEL, QKV_STR, nullptr, nullptr);

    attn_k<<<dim3(SEQ / 128, NHEAD, NB), 256, 0, stream>>>(QKVB, YB);

    gemm_nt<0, 0, 0><<<dim3(64, 8), 256, 0, stream>>>(YB, WO, ob, S, nullptr, 0, S, TOKENS, D_MODEL, D_MODEL, nullptr, nullptr);

    ln_k<<<TOKENS, 256, 0, stream>>>(S, n2g, n2b, XFB, XF);

    hipMemsetAsync(AUXB, 0, 64, stream);
    router_k<<<TOKENS / 16, 256, 0, stream>>>(XF, rw, WTS, AUXB, CNT, ELST);

    // sparse top-2 MoE
    for (int e = 0; e < 4; e++) {
        gemm_nt<1, 1, 1><<<dim3(64, 16), 256, 0, stream>>>(
            XFB, WE1 + (size_t)e * MOE_H * D_MODEL, eb1 + e * MOE_H,
            nullptr, nullptr, 0, HB, TOKENS, D_MODEL, MOE_H,
            ELST + e * TOKENS, CNT + e);
        gemm_nt<0, 2, 2><<<dim3(64, 8), 256, 0, stream>>>(
            HB, WE2 + (size_t)e * D_MODEL * MOE_H, eb2 + e * D_MODEL,
            nullptr, WTS + e, 4, S, TOKENS, MOE_H, D_MODEL,
            ELST + e * TOKENS, CNT + e);
    }

    final_k<<<dim3(SEQ, NB), 256, 0, stream>>>(S, Tr, tw, tb, (float*)d_out);
    aux_k<<<1, 64, 0, stream>>>(AUXB, (float*)d_out + (out_size - 1));
}